// Round 19
// baseline (79451.471 us; speedup 1.0000x reference)
//
#include <hip/hip_runtime.h>
#include <hip/hip_cooperative_groups.h>

namespace cg = cooperative_groups;

constexpr int kB = 64, kS = 2048, kD = 512, kL = 4;
constexpr int kR = 8;                                  // ring depth (time slots)
constexpr int RING_F = kR * kL * kB * kD;              // 4 MB
constexpr int ZBUF_F = kB * kD;                        // 128 KB
constexpr int CNT_N  = kL * 8 * kS;                    // 65536 counters
constexpr size_t NEED_WS = (size_t)(RING_F + ZBUF_F + CNT_N) * 4 + 4096;

// CONFIRMED reference tanh (R15/R16): XLA EmitFastTanh with_fma=true.
__device__ __forceinline__ float tanh_ref(float x0) {
#pragma clang fp contract(off)
  const float kMax = 7.99881172180175781f;
  float xc = fminf(fmaxf(x0, -kMax), kMax);
  float x2 = xc * xc;
  float p = -2.76076847742355e-16f;
  p = fmaf(x2, p, 2.00018790482477e-13f);
  p = fmaf(x2, p, -8.60467152213735e-11f);
  p = fmaf(x2, p, 5.12229709037114e-08f);
  p = fmaf(x2, p, 1.48572235717979e-05f);
  p = fmaf(x2, p, 6.37261928875436e-04f);
  p = fmaf(x2, p, 4.89352455891786e-03f);
  float num = xc * p;
  float q = 1.19825839466702e-06f;
  q = fmaf(x2, q, 1.18534705686654e-04f);
  q = fmaf(x2, q, 2.26843463243900e-03f);
  q = fmaf(x2, q, 4.89352518554385e-03f);
  float r = num / q;
  return (fabsf(x0) < 0.0004f) ? x0 : r;
}

__global__ void prep_zero(float* __restrict__ zbuf, unsigned* __restrict__ cnt) {
  const int gid = blockIdx.x * blockDim.x + threadIdx.x;
  for (int i = gid; i < ZBUF_F; i += gridDim.x * blockDim.x) zbuf[i] = 0.f;
  for (int i = gid; i < CNT_N; i += gridDim.x * blockDim.x) cnt[i] = 0u;
}

__device__ __forceinline__ unsigned cnt_ld(const unsigned* p) {
  return __hip_atomic_load(p, __ATOMIC_RELAXED, __HIP_MEMORY_SCOPE_AGENT);
}

// grid 512 = l(4) x bg(8) x jg(16); block 256 = 8 batches x 32 j.
// Thread -> 1 output (r, j): r = (tid>>5)&..., wave = 2 batches x 32 j.
// Sync: per-(l,bg) counters, 16 jg-producers each, depth-8 ring.
__global__ __launch_bounds__(256, 2) void rnn_pipe2(
    const float* __restrict__ x, const float* __restrict__ Wh,
    const float* __restrict__ Uh, const float* __restrict__ bias,
    float* __restrict__ out, float* __restrict__ ring,
    float* __restrict__ zbuf, unsigned* __restrict__ cnt) {
  const int tid = threadIdx.x, bid = blockIdx.x;
  const int l  = bid >> 7;          // 0..3
  const int bg = (bid >> 4) & 7;    // 0..7
  const int jg = bid & 15;          // 0..15
  const int r  = tid >> 5;          // 0..7 batch row within group
  const int jl = tid & 31;          // 0..31
  const int j  = jg * 32 + jl;
  const int b  = bg * 8 + r;

  __shared__ float iS[8][512];
  __shared__ float hS[8][512];

  const float* Wcol = Wh + (long)l * kD * kD + j;
  const float* Ucol = Uh + (long)l * kD * kD + j;
  const float bv = bias[l * kD + j];

  const unsigned* cSibling = cnt + ((long)l * 8 + bg) * kS;
  const unsigned* cBelow   = (l > 0) ? cnt + ((long)(l - 1) * 8 + bg) * kS : nullptr;
  const unsigned* cAbove   = (l < kL - 1) ? cnt + ((long)(l + 1) * 8 + bg) * kS : nullptr;
  unsigned* cMine = cnt + ((long)l * 8 + bg) * kS;

  for (int t = 0; t < kS; ++t) {
    if (tid == 0) {
      if (t > 0)             while (cnt_ld(&cSibling[t - 1]) < 16u) __builtin_amdgcn_s_sleep(1);
      if (l > 0)             while (cnt_ld(&cBelow[t]) < 16u)       __builtin_amdgcn_s_sleep(1);
      if (cAbove && t >= kR) while (cnt_ld(&cAbove[t - kR]) < 16u)  __builtin_amdgcn_s_sleep(1);
      __threadfence();
    }
    __syncthreads();

    const int slot  = t & (kR - 1);
    const int slotP = (t - 1) & (kR - 1);
    const float* ibase = (l == 0)
        ? nullptr
        : ring + (((long)slot * kL + (l - 1)) * kB + bg * 8) * (long)kD;
    const float* hbase = (t == 0)
        ? zbuf + (long)(bg * 8) * kD
        : ring + (((long)slotP * kL + l) * kB + bg * 8) * (long)kD;
    for (int i = tid; i < 8 * 128; i += 256) {
      const int rr = i >> 7, q4 = (i & 127) * 4;
      const float* isrc = (l == 0)
          ? (x + ((long)(bg * 8 + rr) * kS + t) * kD + q4)
          : (ibase + (long)rr * kD + q4);
      *(float4*)&iS[rr][q4] = *(const float4*)isrc;
      *(float4*)&hS[rr][q4] = *(const float4*)(hbase + (long)rr * kD + q4);
    }
    __syncthreads();

    // ---- bit-exact ascending-k chains, unroll 8, b128 LDS act reads ----
    float dw, du;
    {
#pragma clang fp contract(off)
      dw = 0.f; du = 0.f;
      for (int k = 0; k < 512; k += 8) {
        // issue all 16 weight loads first (16 in flight)
        const float w0 = Wcol[(long)(k + 0) * kD];
        const float w1 = Wcol[(long)(k + 1) * kD];
        const float w2 = Wcol[(long)(k + 2) * kD];
        const float w3 = Wcol[(long)(k + 3) * kD];
        const float w4 = Wcol[(long)(k + 4) * kD];
        const float w5 = Wcol[(long)(k + 5) * kD];
        const float w6 = Wcol[(long)(k + 6) * kD];
        const float w7 = Wcol[(long)(k + 7) * kD];
        const float u0 = Ucol[(long)(k + 0) * kD];
        const float u1 = Ucol[(long)(k + 1) * kD];
        const float u2 = Ucol[(long)(k + 2) * kD];
        const float u3 = Ucol[(long)(k + 3) * kD];
        const float u4 = Ucol[(long)(k + 4) * kD];
        const float u5 = Ucol[(long)(k + 5) * kD];
        const float u6 = Ucol[(long)(k + 6) * kD];
        const float u7 = Ucol[(long)(k + 7) * kD];
        const float4 ia = *(const float4*)&iS[r][k];
        const float4 ib = *(const float4*)&iS[r][k + 4];
        const float4 ha = *(const float4*)&hS[r][k];
        const float4 hb = *(const float4*)&hS[r][k + 4];
        // ascending-k order within each chain (bit-exact)
        dw = fmaf(ia.x, w0, dw); du = fmaf(ha.x, u0, du);
        dw = fmaf(ia.y, w1, dw); du = fmaf(ha.y, u1, du);
        dw = fmaf(ia.z, w2, dw); du = fmaf(ha.z, u2, du);
        dw = fmaf(ia.w, w3, dw); du = fmaf(ha.w, u3, du);
        dw = fmaf(ib.x, w4, dw); du = fmaf(hb.x, u4, du);
        dw = fmaf(ib.y, w5, dw); du = fmaf(hb.y, u5, du);
        dw = fmaf(ib.z, w6, dw); du = fmaf(hb.z, u6, du);
        dw = fmaf(ib.w, w7, dw); du = fmaf(hb.w, u7, du);
      }
    }
    float z;
    {
#pragma clang fp contract(off)
      z = (dw + du) + bv;
    }
    const float h = tanh_ref(z);

    ring[(((long)slot * kL + l) * kB + b) * (long)kD + j] = h;
    if (l == kL - 1) out[((long)b * kS + t) * kD + j] = h;

    __syncthreads();
    if (tid == 0) {
      __threadfence();
      atomicAdd(&cMine[t], 1u);
    }
  }
}

// ---------- fallback: R16 kernel verbatim ----------
__global__ __launch_bounds__(256, 1) void rnn_full(
    const float* __restrict__ x, const float* __restrict__ Wh,
    const float* __restrict__ Uh, const float* __restrict__ bias,
    float* __restrict__ out, float* __restrict__ ws) {
  cg::grid_group grid = cg::this_grid();
  float* Hbuf = ws;
  const int tid = threadIdx.x, bid = blockIdx.x;
  const int l = bid >> 6;
  const int bg = (bid >> 3) & 7;
  const int jg = bid & 7;
  const int jl = tid & 63;
  const int bq = tid >> 6;
  const int j = jg * 64 + jl;
  const int b0 = bg * 8 + bq * 2;
  __shared__ float iS[8][512];
  __shared__ float hS[8][512];
  for (int i = bid * 256 + tid; i < 2 * kL * kB * kD; i += 256 * 256) Hbuf[i] = 0.f;
  grid.sync();
  const float* Wcol = Wh + (long)l * kD * kD + j;
  const float* Ucol = Uh + (long)l * kD * kD + j;
  const float bv = bias[l * kD + j];
  for (int w = 0; w < kS + kL - 1; ++w) {
    const int t = w - l;
    if (t >= 0 && t < kS) {
      const int cur = w & 1, prv = cur ^ 1;
      const float* hbase = Hbuf + (((long)prv * kL + l) * kB + bg * 8) * (long)kD;
      const float* ibase = (l == 0) ? nullptr
          : Hbuf + (((long)prv * kL + (l - 1)) * kB + bg * 8) * (long)kD;
      for (int i = tid; i < 8 * 128; i += 256) {
        const int rr = i >> 7, q4 = (i & 127) * 4;
        const float* isrc = (l == 0)
            ? (x + ((long)(bg * 8 + rr) * kS + t) * kD + q4)
            : (ibase + (long)rr * kD + q4);
        *(float4*)&iS[rr][q4] = *(const float4*)isrc;
        *(float4*)&hS[rr][q4] = *(const float4*)(hbase + (long)rr * kD + q4);
      }
      __syncthreads();
      const int r0 = bq * 2, r1 = r0 + 1;
      float dw0, dw1, du0, du1;
      {
#pragma clang fp contract(off)
        dw0 = 0.f; dw1 = 0.f; du0 = 0.f; du1 = 0.f;
#pragma unroll 4
        for (int k = 0; k < 512; ++k) {
          const float wv = Wcol[(long)k * kD];
          const float uv = Ucol[(long)k * kD];
          dw0 = fmaf(iS[r0][k], wv, dw0);
          dw1 = fmaf(iS[r1][k], wv, dw1);
          du0 = fmaf(hS[r0][k], uv, du0);
          du1 = fmaf(hS[r1][k], uv, du1);
        }
      }
      float z0, z1;
      {
#pragma clang fp contract(off)
        z0 = (dw0 + du0) + bv;
        z1 = (dw1 + du1) + bv;
      }
      const float h0 = tanh_ref(z0);
      const float h1 = tanh_ref(z1);
      float* ho = Hbuf + (((long)cur * kL + l) * kB) * (long)kD;
      ho[(long)b0 * kD + j] = h0;
      ho[(long)(b0 + 1) * kD + j] = h1;
      if (l == kL - 1) {
        out[((long)b0 * kS + t) * kD + j] = h0;
        out[((long)(b0 + 1) * kS + t) * kD + j] = h1;
      }
    }
    grid.sync();
  }
}

extern "C" void kernel_launch(void* const* d_in, const int* in_sizes, int n_in,
                              void* d_out, int out_size, void* d_ws, size_t ws_size,
                              hipStream_t stream) {
  const float* x    = (const float*)d_in[0];
  const float* Wh   = (const float*)d_in[1];
  const float* Uh   = (const float*)d_in[2];
  const float* bias = (const float*)d_in[3];
  float* out = (float*)d_out;
  float* ws  = (float*)d_ws;

  if (ws_size >= NEED_WS) {
    float* ring = ws;
    float* zbuf = ws + RING_F;
    unsigned* cnt = (unsigned*)(zbuf + ZBUF_F);

    prep_zero<<<128, 256, 0, stream>>>(zbuf, cnt);

    void* args[] = {(void*)&x, (void*)&Wh, (void*)&Uh, (void*)&bias,
                    (void*)&out, (void*)&ring, (void*)&zbuf, (void*)&cnt};
    hipLaunchCooperativeKernel((void*)rnn_pipe2, dim3(512), dim3(256), args, 0,
                               stream);
  } else {
    void* args[] = {(void*)&x, (void*)&Wh, (void*)&Uh, (void*)&bias,
                    (void*)&out, (void*)&ws};
    hipLaunchCooperativeKernel((void*)rnn_full, dim3(256), dim3(256), args, 0,
                               stream);
  }
}

// Round 20
// 48864.471 us; speedup vs baseline: 1.6260x; 1.6260x over previous
//
#include <hip/hip_runtime.h>
#include <hip/hip_cooperative_groups.h>

namespace cg = cooperative_groups;

constexpr int kB = 64, kS = 2048, kD = 512, kL = 4;
constexpr int kR = 8;                                  // ring depth (time slots)
constexpr int RING_F = kR * kL * kB * kD;              // 4 MB
constexpr int ZBUF_F = kB * kD;                        // 128 KB
constexpr int CNT_N  = kL * 8 * kS;                    // 65536 counters
constexpr size_t NEED_WS = (size_t)(RING_F + ZBUF_F + CNT_N) * 4 + 4096;

// CONFIRMED reference tanh (R15/R16): XLA EmitFastTanh with_fma=true.
__device__ __forceinline__ float tanh_ref(float x0) {
#pragma clang fp contract(off)
  const float kMax = 7.99881172180175781f;
  float xc = fminf(fmaxf(x0, -kMax), kMax);
  float x2 = xc * xc;
  float p = -2.76076847742355e-16f;
  p = fmaf(x2, p, 2.00018790482477e-13f);
  p = fmaf(x2, p, -8.60467152213735e-11f);
  p = fmaf(x2, p, 5.12229709037114e-08f);
  p = fmaf(x2, p, 1.48572235717979e-05f);
  p = fmaf(x2, p, 6.37261928875436e-04f);
  p = fmaf(x2, p, 4.89352455891786e-03f);
  float num = xc * p;
  float q = 1.19825839466702e-06f;
  q = fmaf(x2, q, 1.18534705686654e-04f);
  q = fmaf(x2, q, 2.26843463243900e-03f);
  q = fmaf(x2, q, 4.89352518554385e-03f);
  float r = num / q;
  return (fabsf(x0) < 0.0004f) ? x0 : r;
}

__global__ void prep_zero(float* __restrict__ zbuf, unsigned* __restrict__ cnt) {
  const int gid = blockIdx.x * blockDim.x + threadIdx.x;
  for (int i = gid; i < ZBUF_F; i += gridDim.x * blockDim.x) zbuf[i] = 0.f;
  for (int i = gid; i < CNT_N; i += gridDim.x * blockDim.x) cnt[i] = 0u;
}

__device__ __forceinline__ unsigned cnt_ld(const unsigned* p) {
  return __hip_atomic_load(p, __ATOMIC_RELAXED, __HIP_MEMORY_SCOPE_AGENT);
}

// broadcast lane kk of a float VGPR to all lanes (bit-exact, VALU pipe)
__device__ __forceinline__ float lane_bcast(float v, int kk) {
  return __uint_as_float(__builtin_amdgcn_readlane(__float_as_uint(v), kk));
}

// grid 256 = l(4) x bg(8) x jg(8); block 256 = 4 waves(bq) x 64 lanes(jl).
// Thread -> outputs (b0,j),(b0+1,j): b0 = bg*8+bq*2, j = jg*64+jl.
// NO LDS: act chunks via per-lane coalesced loads + v_readlane broadcast;
// weights coalesced [k][j] loads, L1-shared across the 4 waves (same j range).
__global__ __launch_bounds__(256, 1) void rnn_pipe3(
    const float* __restrict__ x, const float* __restrict__ Wh,
    const float* __restrict__ Uh, const float* __restrict__ bias,
    float* __restrict__ out, float* __restrict__ ring,
    float* __restrict__ zbuf, unsigned* __restrict__ cnt) {
  const int tid = threadIdx.x, bid = blockIdx.x;
  const int l  = bid >> 6;
  const int bg = (bid >> 3) & 7;
  const int jg = bid & 7;
  const int jl = tid & 63;        // lane id within wave
  const int bq = tid >> 6;        // wave id
  const int j  = jg * 64 + jl;
  const int b0 = bg * 8 + bq * 2;
  const int b1 = b0 + 1;

  const float* Wcol = Wh + (long)l * kD * kD + j;
  const float* Ucol = Uh + (long)l * kD * kD + j;
  const float bv = bias[l * kD + j];

  const unsigned* cSibling = cnt + ((long)l * 8 + bg) * kS;
  const unsigned* cBelow   = (l > 0) ? cnt + ((long)(l - 1) * 8 + bg) * kS : nullptr;
  const unsigned* cAbove   = (l < kL - 1) ? cnt + ((long)(l + 1) * 8 + bg) * kS : nullptr;
  unsigned* cMine = cnt + ((long)l * 8 + bg) * kS;

  for (int t = 0; t < kS; ++t) {
    if (tid == 0) {
      if (t > 0)             while (cnt_ld(&cSibling[t - 1]) < 8u) __builtin_amdgcn_s_sleep(1);
      if (l > 0)             while (cnt_ld(&cBelow[t]) < 8u)       __builtin_amdgcn_s_sleep(1);
      if (cAbove && t >= kR) while (cnt_ld(&cAbove[t - kR]) < 8u)  __builtin_amdgcn_s_sleep(1);
      __threadfence();
    }
    __syncthreads();

    const int slot  = t & (kR - 1);
    const int slotP = (t - 1) & (kR - 1);
    const float* i0row, *i1row;
    if (l == 0) {
      i0row = x + ((long)b0 * kS + t) * kD;
      i1row = x + ((long)b1 * kS + t) * kD;
    } else {
      i0row = ring + (((long)slot * kL + (l - 1)) * kB + b0) * (long)kD;
      i1row = i0row + kD;
    }
    const float* h0row = (t == 0)
        ? zbuf + (long)b0 * kD
        : ring + (((long)slotP * kL + l) * kB + b0) * (long)kD;
    const float* h1row = h0row + kD;

    float dw0, dw1, du0, du1;
    {
#pragma clang fp contract(off)
      dw0 = 0.f; dw1 = 0.f; du0 = 0.f; du1 = 0.f;
      // prefetch chunk 0 (per-lane coalesced: lane = k within chunk)
      float ni0 = i0row[jl], ni1 = i1row[jl];
      float nh0 = h0row[jl], nh1 = h1row[jl];
      for (int ch = 0; ch < 8; ++ch) {
        const float vi0 = ni0, vi1 = ni1, vh0 = nh0, vh1 = nh1;
        if (ch < 7) {  // uniform branch: prefetch next chunk
          const int nb = (ch + 1) * 64 + jl;
          ni0 = i0row[nb]; ni1 = i1row[nb];
          nh0 = h0row[nb]; nh1 = h1row[nb];
        }
        const int base = ch * 64;
#pragma unroll
        for (int kk = 0; kk < 64; ++kk) {
          const float wv = Wcol[(long)(base + kk) * kD];
          const float uv = Ucol[(long)(base + kk) * kD];
          const float ai0 = lane_bcast(vi0, kk);
          const float ai1 = lane_bcast(vi1, kk);
          const float ah0 = lane_bcast(vh0, kk);
          const float ah1 = lane_bcast(vh1, kk);
          dw0 = fmaf(ai0, wv, dw0);
          dw1 = fmaf(ai1, wv, dw1);
          du0 = fmaf(ah0, uv, du0);
          du1 = fmaf(ah1, uv, du1);
        }
      }
    }
    float z0, z1;
    {
#pragma clang fp contract(off)
      z0 = (dw0 + du0) + bv;
      z1 = (dw1 + du1) + bv;
    }
    const float h0 = tanh_ref(z0);
    const float h1 = tanh_ref(z1);

    float* ho = ring + (((long)slot * kL + l) * kB) * (long)kD;
    ho[(long)b0 * kD + j] = h0;
    ho[(long)b1 * kD + j] = h1;
    if (l == kL - 1) {
      out[((long)b0 * kS + t) * kD + j] = h0;
      out[((long)b1 * kS + t) * kD + j] = h1;
    }

    __syncthreads();
    if (tid == 0) {
      __threadfence();
      atomicAdd(&cMine[t], 1u);
    }
  }
}

// ---------- fallback: R16 kernel verbatim ----------
__global__ __launch_bounds__(256, 1) void rnn_full(
    const float* __restrict__ x, const float* __restrict__ Wh,
    const float* __restrict__ Uh, const float* __restrict__ bias,
    float* __restrict__ out, float* __restrict__ ws) {
  cg::grid_group grid = cg::this_grid();
  float* Hbuf = ws;
  const int tid = threadIdx.x, bid = blockIdx.x;
  const int l = bid >> 6;
  const int bg = (bid >> 3) & 7;
  const int jg = bid & 7;
  const int jl = tid & 63;
  const int bq = tid >> 6;
  const int j = jg * 64 + jl;
  const int b0 = bg * 8 + bq * 2;
  __shared__ float iS[8][512];
  __shared__ float hS[8][512];
  for (int i = bid * 256 + tid; i < 2 * kL * kB * kD; i += 256 * 256) Hbuf[i] = 0.f;
  grid.sync();
  const float* Wcol = Wh + (long)l * kD * kD + j;
  const float* Ucol = Uh + (long)l * kD * kD + j;
  const float bv = bias[l * kD + j];
  for (int w = 0; w < kS + kL - 1; ++w) {
    const int t = w - l;
    if (t >= 0 && t < kS) {
      const int cur = w & 1, prv = cur ^ 1;
      const float* hbase = Hbuf + (((long)prv * kL + l) * kB + bg * 8) * (long)kD;
      const float* ibase = (l == 0) ? nullptr
          : Hbuf + (((long)prv * kL + (l - 1)) * kB + bg * 8) * (long)kD;
      for (int i = tid; i < 8 * 128; i += 256) {
        const int rr = i >> 7, q4 = (i & 127) * 4;
        const float* isrc = (l == 0)
            ? (x + ((long)(bg * 8 + rr) * kS + t) * kD + q4)
            : (ibase + (long)rr * kD + q4);
        *(float4*)&iS[rr][q4] = *(const float4*)isrc;
        *(float4*)&hS[rr][q4] = *(const float4*)(hbase + (long)rr * kD + q4);
      }
      __syncthreads();
      const int r0 = bq * 2, r1 = r0 + 1;
      float dw0, dw1, du0, du1;
      {
#pragma clang fp contract(off)
        dw0 = 0.f; dw1 = 0.f; du0 = 0.f; du1 = 0.f;
#pragma unroll 4
        for (int k = 0; k < 512; ++k) {
          const float wv = Wcol[(long)k * kD];
          const float uv = Ucol[(long)k * kD];
          dw0 = fmaf(iS[r0][k], wv, dw0);
          dw1 = fmaf(iS[r1][k], wv, dw1);
          du0 = fmaf(hS[r0][k], uv, du0);
          du1 = fmaf(hS[r1][k], uv, du1);
        }
      }
      float z0, z1;
      {
#pragma clang fp contract(off)
        z0 = (dw0 + du0) + bv;
        z1 = (dw1 + du1) + bv;
      }
      const float h0 = tanh_ref(z0);
      const float h1 = tanh_ref(z1);
      float* ho = Hbuf + (((long)cur * kL + l) * kB) * (long)kD;
      ho[(long)b0 * kD + j] = h0;
      ho[(long)(b0 + 1) * kD + j] = h1;
      if (l == kL - 1) {
        out[((long)b0 * kS + t) * kD + j] = h0;
        out[((long)(b0 + 1) * kS + t) * kD + j] = h1;
      }
    }
    grid.sync();
  }
}

extern "C" void kernel_launch(void* const* d_in, const int* in_sizes, int n_in,
                              void* d_out, int out_size, void* d_ws, size_t ws_size,
                              hipStream_t stream) {
  const float* x    = (const float*)d_in[0];
  const float* Wh   = (const float*)d_in[1];
  const float* Uh   = (const float*)d_in[2];
  const float* bias = (const float*)d_in[3];
  float* out = (float*)d_out;
  float* ws  = (float*)d_ws;

  if (ws_size >= NEED_WS) {
    float* ring = ws;
    float* zbuf = ws + RING_F;
    unsigned* cnt = (unsigned*)(zbuf + ZBUF_F);

    prep_zero<<<128, 256, 0, stream>>>(zbuf, cnt);

    void* args[] = {(void*)&x, (void*)&Wh, (void*)&Uh, (void*)&bias,
                    (void*)&out, (void*)&ring, (void*)&zbuf, (void*)&cnt};
    hipLaunchCooperativeKernel((void*)rnn_pipe3, dim3(256), dim3(256), args, 0,
                               stream);
  } else {
    void* args[] = {(void*)&x, (void*)&Wh, (void*)&Uh, (void*)&bias,
                    (void*)&out, (void*)&ws};
    hipLaunchCooperativeKernel((void*)rnn_full, dim3(256), dim3(256), args, 0,
                               stream);
  }
}